// Round 2
// baseline (515.777 us; speedup 1.0000x reference)
//
#include <hip/hip_runtime.h>

// RoiAlign (TF crop_and_resize, bilinear, extrapolation_value=0)
// boxes: [B, N, 4] f32 pixel coords (x1, y1, x2, y2)
// fpn:   [B, H, W, C] f32 (NHWC, C innermost)
// out:   [B, N, 14, 14, C] f32
//
// R1/R2: nt output stores keep fpn L3-resident (822 MB issued reads vs
//        268 MB distinct; cacheable stores were evicting it).
// R3 (FAILED): in-kernel prefetch blocks. FETCH=465 MB = 268 (prefetch)
//        + 197 (gather misses) — no ordering guarantee, gather raced the
//        prefetch. Kernel 150 -> 174 us. BUT counters showed 49% HBM /
//        34% VALU / 78% occ => the wall is HBM efficiency of scattered
//        2 KB cold fetches, not latency or compute.
// R4:   two stream-serialized launches. Launch 1 streams all of fpn
//        linearly (cacheable -> allocates in the 256 MB memory-side
//        Infinity Cache) at streaming BW. Launch 2 = R2 gather; its
//        822 MB of scattered corner reads now hit L3, HBM sees only the
//        205 MB nt output stream. Predicted: warm ~43 us @ ~6.3 TB/s,
//        gather ~55-75 us with FETCH dropping 465 -> ~20-60 MB.
constexpr int CROP_H = 14;
constexpr int CROP_W = 14;
constexpr int B = 4, N = 256, H = 256, W = 256, C = 256;
constexpr int C4 = C / 4;                                   // float4 per pixel
constexpr int POS_PER_IMG = N * CROP_H * CROP_W;            // 50176
constexpr size_t TOTAL_FLOAT4 = (size_t)B * H * W * C4;     // 16,777,216 float4 = 268 MB

typedef float vfloat4 __attribute__((ext_vector_type(4)));

// ---- Launch 1: linear L3-warming stream of the whole fpn tensor. ----
__global__ __launch_bounds__(256) void warm_fpn_kernel(
    const float* __restrict__ fpn) {
  const float4* __restrict__ src = (const float4*)fpn;
  size_t idx = (size_t)blockIdx.x * blockDim.x + threadIdx.x;
  const size_t stride = (size_t)gridDim.x * blockDim.x;     // 524288
  float acc = 0.0f;
#pragma unroll 4
  for (size_t k = idx; k < TOTAL_FLOAT4; k += stride) {     // 32 iters/thread
    float4 v = src[k];
    acc += v.x + v.y + v.z + v.w;  // consume all lanes of the dwordx4
  }
  asm volatile("" :: "v"(acc));    // sink: keep loads alive (no DCE)
}

// ---- Launch 2: gather. Identical numerics to R2 (absmax-preserving). ----
__global__ __launch_bounds__(256) void roi_align_kernel(
    const float* __restrict__ boxes,
    const float* __restrict__ fpn,
    float* __restrict__ out) {
  // One 64-lane wave per output position (b,n,i,j); lane covers 4 channels.
  const int wave = threadIdx.x >> 6;
  const int lane = threadIdx.x & 63;
  int pos = blockIdx.x * 4 + wave;   // [0, B*N*CROP_H*CROP_W)

  int j = pos % CROP_W;
  int t = pos / CROP_W;
  int i = t % CROP_H;
  t /= CROP_H;
  int n = t % N;
  int b = t / N;

  const float* bx = boxes + (size_t)(b * N + n) * 4;
  float x1 = bx[0], y1 = bx[1], x2 = bx[2], y2 = bx[3];

  // Replicate the reference's exact fp32 normalization sequence.
  const float Hf = (float)H, Wf = (float)W;
  float ny1 = y1 / Hf * Hf / (Hf - 1.0f);
  float nx1 = x1 / Wf * Wf / (Wf - 1.0f);
  float ny2 = (y2 / Hf * Hf - 1.0f) / (Hf - 1.0f);
  float nx2 = (x2 / Wf * Wf - 1.0f) / (Wf - 1.0f);

  float ty = (float)i / (float)(CROP_H - 1);
  float tx = (float)j / (float)(CROP_W - 1);
  float ys = (ny1 + (ny2 - ny1) * ty) * (Hf - 1.0f);
  float xs = (nx1 + (nx2 - nx1) * tx) * (Wf - 1.0f);

  bool valid = (ys >= 0.0f) && (ys <= Hf - 1.0f) &&
               (xs >= 0.0f) && (xs <= Wf - 1.0f);

  float y0f = floorf(ys), x0f = floorf(xs);
  float wy = ys - y0f, wx = xs - x0f;
  int y0  = (int)fminf(fmaxf(y0f,        0.0f), Hf - 1.0f);
  int y1i = (int)fminf(fmaxf(y0f + 1.0f, 0.0f), Hf - 1.0f);
  int x0  = (int)fminf(fmaxf(x0f,        0.0f), Wf - 1.0f);
  int x1i = (int)fminf(fmaxf(x0f + 1.0f, 0.0f), Wf - 1.0f);

  const float4* f4 = (const float4*)fpn;
  int rb = b * H;
  size_t i00 = (size_t)((rb + y0)  * W + x0)  * C4 + lane;
  size_t i01 = (size_t)((rb + y0)  * W + x1i) * C4 + lane;
  size_t i10 = (size_t)((rb + y1i) * W + x0)  * C4 + lane;
  size_t i11 = (size_t)((rb + y1i) * W + x1i) * C4 + lane;

  float4 tl = f4[i00];
  float4 tr = f4[i01];
  float4 bl = f4[i10];
  float4 br = f4[i11];

  float w00 = (1.0f - wy) * (1.0f - wx);
  float w01 = (1.0f - wy) * wx;
  float w10 = wy * (1.0f - wx);
  float w11 = wy * wx;

  vfloat4 o;
  o.x = tl.x * w00 + tr.x * w01 + bl.x * w10 + br.x * w11;
  o.y = tl.y * w00 + tr.y * w01 + bl.y * w10 + br.y * w11;
  o.z = tl.z * w00 + tr.z * w01 + bl.z * w10 + br.z * w11;
  o.w = tl.w * w00 + tr.w * w01 + bl.w * w10 + br.w * w11;
  if (!valid) { o.x = 0.0f; o.y = 0.0f; o.z = 0.0f; o.w = 0.0f; }

  // Non-temporal store: don't let the 205 MB output stream evict fpn from L3.
  vfloat4* dst = (vfloat4*)out + (size_t)pos * C4 + lane;
  __builtin_nontemporal_store(o, dst);
}

extern "C" void kernel_launch(void* const* d_in, const int* in_sizes, int n_in,
                              void* d_out, int out_size, void* d_ws, size_t ws_size,
                              hipStream_t stream) {
  const float* boxes = (const float*)d_in[0];  // [B, N, 4]
  const float* fpn   = (const float*)d_in[1];  // [B, H, W, C]
  float* out = (float*)d_out;                  // [B, N, 14, 14, C]

  // Launch 1: warm L3 with the whole fpn (linear stream, full HBM BW).
  // Stream order guarantees completion before the gather starts — the
  // ordering R3's fused prefetch could not provide.
  hipLaunchKernelGGL(warm_fpn_kernel, dim3(2048), dim3(256), 0, stream, fpn);

  // Launch 2: gather; corner reads now hit the warmed Infinity Cache.
  const int positions = B * N * CROP_H * CROP_W;  // 200704, divisible by 4
  hipLaunchKernelGGL(roi_align_kernel, dim3(positions / 4), dim3(256), 0,
                     stream, boxes, fpn, out);
}